// Round 24
// baseline (76.213 us; speedup 1.0000x reference)
//
#include <hip/hip_runtime.h>
#include <math.h>

#define N_TOK 8192
#define DIM   1024
#define NE    8
#define NR    16
#define NO    3072
#define OUT_ELEMS (N_TOK * NO)   // 25165824

typedef float fx4 __attribute__((ext_vector_type(4)));

__device__ __forceinline__ float softplusf(float z) {
  return z > 0.f ? z + log1pf(expf(-z)) : log1pf(expf(z));
}
__device__ __forceinline__ float ncdf(float z) {
  return 0.5f * erfcf(-z * 0.70710678118654752f);
}

#define FMA4(A, S, W) { (A).x = fmaf((S),(W).x,(A).x); (A).y = fmaf((S),(W).y,(A).y); \
                        (A).z = fmaf((S),(W).z,(A).z); (A).w = fmaf((S),(W).w,(A).w); }
#define DOT4ACC(ACC, X, W) ACC = fmaf((X).x,(W).x, fmaf((X).y,(W).y, fmaf((X).z,(W).z, fmaf((X).w,(W).w,(ACC)))))
#define Z4 make_float4(0.f,0.f,0.f,0.f)

__device__ __forceinline__ void nt_store4(float* p, float4 v) {
  fx4 vv; vv.x = v.x; vv.y = v.y; vv.z = v.z; vv.w = v.w;
  __builtin_nontemporal_store(vv, (fx4*)p);
}

// ---------------------------------------------------------------------------
// kA9: gating GEMM (session-best config). 512 blocks x 16 tokens x 16 outs,
// K=1024 in 8 chunks of 128. Register tile 4 tok x 4 outs.
// ---------------------------------------------------------------------------
__global__ __launch_bounds__(256) void kA9(const float* __restrict__ x,
    const float* __restrict__ wg, const float* __restrict__ wn,
    const float* __restrict__ nz, int* __restrict__ eid, float* __restrict__ part,
    int* __restrict__ fill) {
  __shared__ float xl[16 * 132];        // x chunk [tok][128k] pad 132
  __shared__ float wl[128 * 20];        // W chunk [k][16 outs] pad 20
  __shared__ float accd[16 * 16 * 20];  // [kh][tok][16] partials
  __shared__ float lgS[16 * 20];
  int t = threadIdx.x;
  int n0 = blockIdx.x << 4;
  if (blockIdx.x == 0 && t < 8) fill[t] = 0;
  int tokq = t & 3, og = (t >> 2) & 3, kh = t >> 4;
  int tx = t >> 4, jx = t & 15;
  int kw = t >> 1, hw = t & 1;
  const float* xsrc = x + (size_t)(n0 + tx) * DIM + (jx << 3);
  const float* wsrc = (hw == 0) ? (wg + (size_t)kw * NE) : (wn + (size_t)kw * NE);
  float4 xa0 = *(const float4*)(xsrc);
  float4 xa1 = *(const float4*)(xsrc + 4);
  float4 wa0 = *(const float4*)(wsrc);
  float4 wa1 = *(const float4*)(wsrc + 4);
  float4 acc0 = Z4, acc1 = Z4, acc2 = Z4, acc3 = Z4;   // toks tokq+0/4/8/12
  for (int c = 0; c < 8; ++c) {
    __syncthreads();
    *(float4*)&xl[tx * 132 + (jx << 3)]     = xa0;
    *(float4*)&xl[tx * 132 + (jx << 3) + 4] = xa1;
    *(float4*)&wl[kw * 20 + (hw << 3)]      = wa0;
    *(float4*)&wl[kw * 20 + (hw << 3) + 4]  = wa1;
    __syncthreads();
    if (c < 7) {
      int xo = (c + 1) << 7;
      xa0 = *(const float4*)(xsrc + xo);
      xa1 = *(const float4*)(xsrc + xo + 4);
      int wo = (c + 1) << 10;
      wa0 = *(const float4*)(wsrc + wo);
      wa1 = *(const float4*)(wsrc + wo + 4);
    }
    #pragma unroll
    for (int k4 = 0; k4 < 2; ++k4) {
      int kk = (kh << 3) + (k4 << 2);
      float4 xv0 = *(const float4*)&xl[(tokq +  0) * 132 + kk];
      float4 xv1 = *(const float4*)&xl[(tokq +  4) * 132 + kk];
      float4 xv2 = *(const float4*)&xl[(tokq +  8) * 132 + kk];
      float4 xv3 = *(const float4*)&xl[(tokq + 12) * 132 + kk];
      const float* wb = &wl[kk * 20 + (og << 2)];
      float4 w0 = *(const float4*)(wb + 0);
      float4 w1 = *(const float4*)(wb + 20);
      float4 w2 = *(const float4*)(wb + 40);
      float4 w3 = *(const float4*)(wb + 60);
      FMA4(acc0, xv0.x, w0); FMA4(acc0, xv0.y, w1); FMA4(acc0, xv0.z, w2); FMA4(acc0, xv0.w, w3);
      FMA4(acc1, xv1.x, w0); FMA4(acc1, xv1.y, w1); FMA4(acc1, xv1.z, w2); FMA4(acc1, xv1.w, w3);
      FMA4(acc2, xv2.x, w0); FMA4(acc2, xv2.y, w1); FMA4(acc2, xv2.z, w2); FMA4(acc2, xv2.w, w3);
      FMA4(acc3, xv3.x, w0); FMA4(acc3, xv3.y, w1); FMA4(acc3, xv3.z, w2); FMA4(acc3, xv3.w, w3);
    }
  }
  { int b = kh * 320 + (og << 2);
    *(float4*)&accd[b + (tokq +  0) * 20] = acc0;
    *(float4*)&accd[b + (tokq +  4) * 20] = acc1;
    *(float4*)&accd[b + (tokq +  8) * 20] = acc2;
    *(float4*)&accd[b + (tokq + 12) * 20] = acc3; }
  __syncthreads();
  { int ts = t >> 4, o = t & 15;
    float s = 0.f;
    #pragma unroll
    for (int k2 = 0; k2 < 16; ++k2) s += accd[k2 * 320 + ts * 20 + o];
    lgS[ts * 20 + o] = s; }
  __syncthreads();
  if (t < 16) {
    int n = n0 + t;
    float cl[8], st[8], lg[8];
    float4 nzv0 = *(const float4*)(nz + (size_t)n * NE);
    float4 nzv1 = *(const float4*)(nz + (size_t)n * NE + 4);
    float nzv[8] = {nzv0.x, nzv0.y, nzv0.z, nzv0.w, nzv1.x, nzv1.y, nzv1.z, nzv1.w};
    #pragma unroll
    for (int e = 0; e < 8; ++e) cl[e] = lgS[t * 20 + e];
    #pragma unroll
    for (int e = 0; e < 8; ++e) {
      st[e] = softplusf(lgS[t * 20 + 8 + e]) + 0.01f;
      lg[e] = fmaf(nzv[e], st[e], cl[e]);
    }
    float m1 = -1e30f, m2 = -1e30f; int idx = 0;
    #pragma unroll
    for (int e = 0; e < 8; ++e) {
      float v = lg[e];
      if (v > m1)      { m2 = m1; m1 = v; idx = e; }
      else if (v > m2) { m2 = v; }
    }
    eid[n] = idx;
    float pr[8], cw[8];
    #pragma unroll
    for (int e = 0; e < 8; ++e) {
      float thr = (lg[e] > m2) ? m2 : m1;
      pr[e] = ncdf((cl[e] - thr) / st[e]);
    }
    #pragma unroll
    for (int e = 0; e < 8; ++e) cw[e] = (float)__popcll(__ballot(idx == e));
    #pragma unroll
    for (int e = 0; e < 8; ++e) {
      #pragma unroll
      for (int off = 1; off <= 8; off <<= 1) pr[e] += __shfl_xor(pr[e], off);
    }
    if (t == 0) {
      #pragma unroll
      for (int e = 0; e < 8; ++e) {
        part[blockIdx.x * 16 + e]     = cw[e];
        part[blockIdx.x * 16 + 8 + e] = pr[e];
      }
    }
  }
}

// ---------------------------------------------------------------------------
// kC: fused counts reduction (512x16 partials) + bucket scatter. 32 blocks.
// ---------------------------------------------------------------------------
__global__ __launch_bounds__(256) void kC(const float* __restrict__ part,
    const int* __restrict__ eid, int* __restrict__ fill, int* __restrict__ bucket,
    float* __restrict__ outIL, int* __restrict__ counts) {
  __shared__ float red[16][16];
  __shared__ int cnt_s[8], lcnt[8], lbase[8];
  int t = threadIdx.x;
  int s = t & 15, g = t >> 4;
  float sum = 0.f;
  #pragma unroll
  for (int j = 0; j < 32; ++j) sum += part[(g + 16 * j) * 16 + s];
  red[g][s] = sum;
  if (t < 8) lcnt[t] = 0;
  __syncthreads();
  if (t < 16) {
    float tot = 0.f;
    #pragma unroll
    for (int gg = 0; gg < 16; ++gg) tot += red[gg][t];
    if (blockIdx.x == 0) outIL[t] = tot;
    if (t < 8) {
      cnt_s[t] = (int)(tot + 0.5f);
      if (blockIdx.x == 0) counts[t] = (int)(tot + 0.5f);
    }
  }
  __syncthreads();
  int n = blockIdx.x * 256 + t;
  int e = eid[n];
  int rank = atomicAdd(&lcnt[e], 1);
  __syncthreads();
  if (t < 8) lbase[t] = atomicAdd(&fill[t], lcnt[t]);
  __syncthreads();
  int off = 0;
  #pragma unroll
  for (int i = 0; i < 8; ++i) if (i < e) off += cnt_s[i];
  bucket[off + lbase[e] + rank] = n;
}

// ---------------------------------------------------------------------------
// kD9: h_sorted = lora_a[e] @ x[bucket]. 519 blocks, 16 sorted tokens/tile;
// register tile 4 tok x 4 r.
// ---------------------------------------------------------------------------
__global__ __launch_bounds__(256) void kD9(const float* __restrict__ x,
    const float* __restrict__ la, const int* __restrict__ counts,
    const int* __restrict__ bucket, float* __restrict__ h) {
  __shared__ float xl[16 * 132];
  __shared__ float wl[16 * 132];
  __shared__ float accd[16 * 16 * 20];
  __shared__ float hS[16 * 20];
  __shared__ int toks[16];
  int tile = blockIdx.x;
  int e = -1, jt = 0, off = 0;
  { int tot = 0, o = 0;
    #pragma unroll
    for (int i = 0; i < 8; ++i) {
      int c = counts[i]; int nt = (c + 15) >> 4;
      if (e < 0 && tile < tot + nt) { e = i; jt = tile - tot; off = o; }
      tot += nt; o += c;
    } }
  if (e < 0) return;
  int cnt = counts[e];
  int p0 = off + (jt << 4);
  int valid = min(16, cnt - (jt << 4));
  int t = threadIdx.x;
  if (t < 16) toks[t] = bucket[p0 + min(t, valid - 1)];
  __syncthreads();
  int tokq = t & 3, rg = (t >> 2) & 3, kh = t >> 4;
  int tx = t >> 4, jx = t & 15;
  const float* xsrc = x + (size_t)toks[tx] * DIM + (jx << 3);
  const float* wsrc = la + (size_t)e * (NR * DIM) + (size_t)tx * DIM + (jx << 3);
  float4 xa0 = *(const float4*)(xsrc);
  float4 xa1 = *(const float4*)(xsrc + 4);
  float4 wa0 = *(const float4*)(wsrc);
  float4 wa1 = *(const float4*)(wsrc + 4);
  float4 acc0 = Z4, acc1 = Z4, acc2 = Z4, acc3 = Z4;
  for (int c = 0; c < 8; ++c) {
    __syncthreads();
    *(float4*)&xl[tx * 132 + (jx << 3)]     = xa0;
    *(float4*)&xl[tx * 132 + (jx << 3) + 4] = xa1;
    *(float4*)&wl[tx * 132 + (jx << 3)]     = wa0;
    *(float4*)&wl[tx * 132 + (jx << 3) + 4] = wa1;
    __syncthreads();
    if (c < 7) {
      int ko = (c + 1) << 7;
      xa0 = *(const float4*)(xsrc + ko);
      xa1 = *(const float4*)(xsrc + ko + 4);
      wa0 = *(const float4*)(wsrc + ko);
      wa1 = *(const float4*)(wsrc + ko + 4);
    }
    #pragma unroll
    for (int k4 = 0; k4 < 2; ++k4) {
      int kk = (kh << 3) + (k4 << 2);
      float4 xv0 = *(const float4*)&xl[(tokq +  0) * 132 + kk];
      float4 xv1 = *(const float4*)&xl[(tokq +  4) * 132 + kk];
      float4 xv2 = *(const float4*)&xl[(tokq +  8) * 132 + kk];
      float4 xv3 = *(const float4*)&xl[(tokq + 12) * 132 + kk];
      const float* wb = &wl[(rg << 2) * 132 + kk];
      float4 a0 = *(const float4*)(wb + 0);
      float4 a1 = *(const float4*)(wb + 132);
      float4 a2 = *(const float4*)(wb + 264);
      float4 a3 = *(const float4*)(wb + 396);
      DOT4ACC(acc0.x, xv0, a0); DOT4ACC(acc0.y, xv0, a1); DOT4ACC(acc0.z, xv0, a2); DOT4ACC(acc0.w, xv0, a3);
      DOT4ACC(acc1.x, xv1, a0); DOT4ACC(acc1.y, xv1, a1); DOT4ACC(acc1.z, xv1, a2); DOT4ACC(acc1.w, xv1, a3);
      DOT4ACC(acc2.x, xv2, a0); DOT4ACC(acc2.y, xv2, a1); DOT4ACC(acc2.z, xv2, a2); DOT4ACC(acc2.w, xv2, a3);
      DOT4ACC(acc3.x, xv3, a0); DOT4ACC(acc3.y, xv3, a1); DOT4ACC(acc3.z, xv3, a2); DOT4ACC(acc3.w, xv3, a3);
    }
  }
  { int b = kh * 320 + (rg << 2);
    *(float4*)&accd[b + (tokq +  0) * 20] = acc0;
    *(float4*)&accd[b + (tokq +  4) * 20] = acc1;
    *(float4*)&accd[b + (tokq +  8) * 20] = acc2;
    *(float4*)&accd[b + (tokq + 12) * 20] = acc3; }
  __syncthreads();
  { int ts = t >> 4, rr = t & 15;
    float s = 0.f;
    #pragma unroll
    for (int k2 = 0; k2 < 16; ++k2) s += accd[k2 * 320 + ts * 20 + rr];
    hS[ts * 20 + rr] = s; }
  __syncthreads();
  if (t < 64) {
    int tk = t >> 2, rq = (t & 3) << 2;
    if (tk < valid) {
      float4 v = make_float4(hS[tk * 20 + rq + 0], hS[tk * 20 + rq + 1],
                             hS[tk * 20 + rq + 2], hS[tk * 20 + rq + 3]);
      *(float4*)(h + (size_t)(p0 + tk) * NR + rq) = v;
    }
  }
}

// ---------------------------------------------------------------------------
// kE: out[n] = lora_b[e] @ h_sorted. Tiles: 64 tokens x 256 outs.
// out stores are non-temporal (write-once data; avoid L2 alloc/thrash).
// ---------------------------------------------------------------------------
__global__ __launch_bounds__(256) void kE(const float* __restrict__ h,
    const float* __restrict__ lb, const int* __restrict__ counts,
    const int* __restrict__ bucket, float* __restrict__ out) {
  __shared__ float bt[16][260];
  __shared__ float ht[16][64];
  __shared__ int toks[64];
  int tile = blockIdx.y;
  int e = -1, jt = 0, off = 0;
  { int tot = 0, o = 0;
    #pragma unroll
    for (int i = 0; i < 8; ++i) {
      int c = counts[i]; int nt = (c + 63) >> 6;
      if (e < 0 && tile < tot + nt) { e = i; jt = tile - tot; off = o; }
      tot += nt; o += c;
    } }
  if (e < 0) return;
  int cnt = counts[e];
  int p0 = off + (jt << 6);
  int valid = min(64, cnt - (jt << 6));
  int o0 = blockIdx.x << 8;
  int t = threadIdx.x;
  if (t < 64) toks[t] = bucket[p0 + min(t, valid - 1)];
  const float* bbase = lb + ((size_t)e * NO + o0) * NR;
  #pragma unroll
  for (int kk = 0; kk < 4; ++kk) {
    int idx = (kk << 8) + t;
    int o = idx >> 2, rq = (idx & 3) << 2;
    float4 v = *(const float4*)(bbase + o * NR + rq);
    bt[rq + 0][o] = v.x; bt[rq + 1][o] = v.y; bt[rq + 2][o] = v.z; bt[rq + 3][o] = v.w;
  }
  { int tok = t >> 2, rq = (t & 3) << 2;
    float4 v = *(const float4*)(h + (size_t)(p0 + min(tok, valid - 1)) * NR + rq);
    ht[rq + 0][tok] = v.x; ht[rq + 1][tok] = v.y; ht[rq + 2][tok] = v.z; ht[rq + 3][tok] = v.w; }
  __syncthreads();
  int og = t & 31, tokg = t >> 5;
  int ob = og << 2, tb = tokg << 3;
  float4 z = Z4;
  float4 aL0=z,aL1=z,aL2=z,aL3=z,aL4=z,aL5=z,aL6=z,aL7=z;
  float4 aH0=z,aH1=z,aH2=z,aH3=z,aH4=z,aH5=z,aH6=z,aH7=z;
  #pragma unroll
  for (int r = 0; r < 16; ++r) {
    float4 blo = *(const float4*)&bt[r][ob];
    float4 bhi = *(const float4*)&bt[r][ob + 128];
    float4 h0  = *(const float4*)&ht[r][tb];
    float4 h1  = *(const float4*)&ht[r][tb + 4];
    FMA4(aL0, h0.x, blo); FMA4(aH0, h0.x, bhi);
    FMA4(aL1, h0.y, blo); FMA4(aH1, h0.y, bhi);
    FMA4(aL2, h0.z, blo); FMA4(aH2, h0.z, bhi);
    FMA4(aL3, h0.w, blo); FMA4(aH3, h0.w, bhi);
    FMA4(aL4, h1.x, blo); FMA4(aH4, h1.x, bhi);
    FMA4(aL5, h1.y, blo); FMA4(aH5, h1.y, bhi);
    FMA4(aL6, h1.z, blo); FMA4(aH6, h1.z, bhi);
    FMA4(aL7, h1.w, blo); FMA4(aH7, h1.w, bhi);
  }
  #define ST(J, AL, AH) { int tt = tb + (J); if (tt < valid) { \
      float* p = out + (size_t)toks[tt] * NO + o0 + ob; \
      nt_store4(p, (AL)); \
      nt_store4(p + 128, (AH)); } }
  ST(0, aL0, aH0); ST(1, aL1, aH1); ST(2, aL2, aH2); ST(3, aL3, aH3);
  ST(4, aL4, aH4); ST(5, aL5, aH5); ST(6, aL6, aH6); ST(7, aL7, aH7);
  #undef ST
}

// ---------------------------------------------------------------------------
extern "C" void kernel_launch(void* const* d_in, const int* in_sizes, int n_in,
                              void* d_out, int out_size, void* d_ws, size_t ws_size,
                              hipStream_t stream) {
  const float* x  = (const float*)d_in[0];
  const float* wg = (const float*)d_in[1];
  const float* wn = (const float*)d_in[2];
  const float* la = (const float*)d_in[3];
  const float* lb = (const float*)d_in[4];
  const float* nz = (const float*)d_in[5];
  float* out = (float*)d_out;

  char* ws = (char*)d_ws;
  float* h        = (float*)(ws);                 // 524288 B
  int*   eid      = (int*)  (ws + 524288);        // 32768 B
  int*   bucket   = (int*)  (ws + 557056);        // 32768 B
  float* partials = (float*)(ws + 589824);        // 32768 B (512*16*4)
  int*   counts   = (int*)  (ws + 622592);        // 32 B
  int*   fill     = (int*)  (ws + 622624);        // 32 B

  kA9<<<512, 256, 0, stream>>>(x, wg, wn, nz, eid, partials, fill);
  kC<<<32, 256, 0, stream>>>(partials, eid, fill, bucket, out + OUT_ELEMS, counts);
  kD9<<<519, 256, 0, stream>>>(x, la, counts, bucket, h);
  kE<<<dim3(12, 135), 256, 0, stream>>>(h, lb, counts, bucket, out);
}

// Round 25
// 71.789 us; speedup vs baseline: 1.0616x; 1.0616x over previous
//
#include <hip/hip_runtime.h>
#include <math.h>

#define N_TOK 8192
#define DIM   1024
#define NE    8
#define NR    16
#define NO    3072
#define OUT_ELEMS (N_TOK * NO)   // 25165824

__device__ __forceinline__ float softplusf(float z) {
  return z > 0.f ? z + log1pf(expf(-z)) : log1pf(expf(z));
}
__device__ __forceinline__ float ncdf(float z) {
  return 0.5f * erfcf(-z * 0.70710678118654752f);
}

#define FMA4(A, S, W) { (A).x = fmaf((S),(W).x,(A).x); (A).y = fmaf((S),(W).y,(A).y); \
                        (A).z = fmaf((S),(W).z,(A).z); (A).w = fmaf((S),(W).w,(A).w); }
#define DOT4ACC(ACC, X, W) ACC = fmaf((X).x,(W).x, fmaf((X).y,(W).y, fmaf((X).z,(W).z, fmaf((X).w,(W).w,(ACC)))))
#define Z4 make_float4(0.f,0.f,0.f,0.f)

// ---------------------------------------------------------------------------
// kA9: gating GEMM (session-best config, 71.8-72.0 us total, confirmed 3x).
// 512 blocks x 16 tokens x 16 outs, K=1024 in 8 chunks of 128.
// Register tile 4 tok x 4 outs (thread = tokq(4) x og(4) x kh(16)).
// ---------------------------------------------------------------------------
__global__ __launch_bounds__(256) void kA9(const float* __restrict__ x,
    const float* __restrict__ wg, const float* __restrict__ wn,
    const float* __restrict__ nz, int* __restrict__ eid, float* __restrict__ part,
    int* __restrict__ fill) {
  __shared__ float xl[16 * 132];        // x chunk [tok][128k] pad 132
  __shared__ float wl[128 * 20];        // W chunk [k][16 outs] pad 20
  __shared__ float accd[16 * 16 * 20];  // [kh][tok][16] partials
  __shared__ float lgS[16 * 20];
  int t = threadIdx.x;
  int n0 = blockIdx.x << 4;
  if (blockIdx.x == 0 && t < 8) fill[t] = 0;
  int tokq = t & 3, og = (t >> 2) & 3, kh = t >> 4;
  int tx = t >> 4, jx = t & 15;
  int kw = t >> 1, hw = t & 1;
  const float* xsrc = x + (size_t)(n0 + tx) * DIM + (jx << 3);
  const float* wsrc = (hw == 0) ? (wg + (size_t)kw * NE) : (wn + (size_t)kw * NE);
  float4 xa0 = *(const float4*)(xsrc);
  float4 xa1 = *(const float4*)(xsrc + 4);
  float4 wa0 = *(const float4*)(wsrc);
  float4 wa1 = *(const float4*)(wsrc + 4);
  float4 acc0 = Z4, acc1 = Z4, acc2 = Z4, acc3 = Z4;   // toks tokq+0/4/8/12
  for (int c = 0; c < 8; ++c) {
    __syncthreads();
    *(float4*)&xl[tx * 132 + (jx << 3)]     = xa0;
    *(float4*)&xl[tx * 132 + (jx << 3) + 4] = xa1;
    *(float4*)&wl[kw * 20 + (hw << 3)]      = wa0;
    *(float4*)&wl[kw * 20 + (hw << 3) + 4]  = wa1;
    __syncthreads();
    if (c < 7) {
      int xo = (c + 1) << 7;
      xa0 = *(const float4*)(xsrc + xo);
      xa1 = *(const float4*)(xsrc + xo + 4);
      int wo = (c + 1) << 10;
      wa0 = *(const float4*)(wsrc + wo);
      wa1 = *(const float4*)(wsrc + wo + 4);
    }
    #pragma unroll
    for (int k4 = 0; k4 < 2; ++k4) {
      int kk = (kh << 3) + (k4 << 2);
      float4 xv0 = *(const float4*)&xl[(tokq +  0) * 132 + kk];
      float4 xv1 = *(const float4*)&xl[(tokq +  4) * 132 + kk];
      float4 xv2 = *(const float4*)&xl[(tokq +  8) * 132 + kk];
      float4 xv3 = *(const float4*)&xl[(tokq + 12) * 132 + kk];
      const float* wb = &wl[kk * 20 + (og << 2)];
      float4 w0 = *(const float4*)(wb + 0);
      float4 w1 = *(const float4*)(wb + 20);
      float4 w2 = *(const float4*)(wb + 40);
      float4 w3 = *(const float4*)(wb + 60);
      FMA4(acc0, xv0.x, w0); FMA4(acc0, xv0.y, w1); FMA4(acc0, xv0.z, w2); FMA4(acc0, xv0.w, w3);
      FMA4(acc1, xv1.x, w0); FMA4(acc1, xv1.y, w1); FMA4(acc1, xv1.z, w2); FMA4(acc1, xv1.w, w3);
      FMA4(acc2, xv2.x, w0); FMA4(acc2, xv2.y, w1); FMA4(acc2, xv2.z, w2); FMA4(acc2, xv2.w, w3);
      FMA4(acc3, xv3.x, w0); FMA4(acc3, xv3.y, w1); FMA4(acc3, xv3.z, w2); FMA4(acc3, xv3.w, w3);
    }
  }
  { int b = kh * 320 + (og << 2);
    *(float4*)&accd[b + (tokq +  0) * 20] = acc0;
    *(float4*)&accd[b + (tokq +  4) * 20] = acc1;
    *(float4*)&accd[b + (tokq +  8) * 20] = acc2;
    *(float4*)&accd[b + (tokq + 12) * 20] = acc3; }
  __syncthreads();
  { int ts = t >> 4, o = t & 15;
    float s = 0.f;
    #pragma unroll
    for (int k2 = 0; k2 < 16; ++k2) s += accd[k2 * 320 + ts * 20 + o];
    lgS[ts * 20 + o] = s; }
  __syncthreads();
  if (t < 16) {
    int n = n0 + t;
    float cl[8], st[8], lg[8];
    float4 nzv0 = *(const float4*)(nz + (size_t)n * NE);
    float4 nzv1 = *(const float4*)(nz + (size_t)n * NE + 4);
    float nzv[8] = {nzv0.x, nzv0.y, nzv0.z, nzv0.w, nzv1.x, nzv1.y, nzv1.z, nzv1.w};
    #pragma unroll
    for (int e = 0; e < 8; ++e) cl[e] = lgS[t * 20 + e];
    #pragma unroll
    for (int e = 0; e < 8; ++e) {
      st[e] = softplusf(lgS[t * 20 + 8 + e]) + 0.01f;
      lg[e] = fmaf(nzv[e], st[e], cl[e]);
    }
    float m1 = -1e30f, m2 = -1e30f; int idx = 0;
    #pragma unroll
    for (int e = 0; e < 8; ++e) {
      float v = lg[e];
      if (v > m1)      { m2 = m1; m1 = v; idx = e; }
      else if (v > m2) { m2 = v; }
    }
    eid[n] = idx;
    float pr[8], cw[8];
    #pragma unroll
    for (int e = 0; e < 8; ++e) {
      float thr = (lg[e] > m2) ? m2 : m1;
      pr[e] = ncdf((cl[e] - thr) / st[e]);
    }
    #pragma unroll
    for (int e = 0; e < 8; ++e) cw[e] = (float)__popcll(__ballot(idx == e));
    #pragma unroll
    for (int e = 0; e < 8; ++e) {
      #pragma unroll
      for (int off = 1; off <= 8; off <<= 1) pr[e] += __shfl_xor(pr[e], off);
    }
    if (t == 0) {
      #pragma unroll
      for (int e = 0; e < 8; ++e) {
        part[blockIdx.x * 16 + e]     = cw[e];
        part[blockIdx.x * 16 + 8 + e] = pr[e];
      }
    }
  }
}

// ---------------------------------------------------------------------------
// kC: fused counts reduction (512x16 partials) + bucket scatter. 32 blocks.
// ---------------------------------------------------------------------------
__global__ __launch_bounds__(256) void kC(const float* __restrict__ part,
    const int* __restrict__ eid, int* __restrict__ fill, int* __restrict__ bucket,
    float* __restrict__ outIL, int* __restrict__ counts) {
  __shared__ float red[16][16];
  __shared__ int cnt_s[8], lcnt[8], lbase[8];
  int t = threadIdx.x;
  int s = t & 15, g = t >> 4;
  float sum = 0.f;
  #pragma unroll
  for (int j = 0; j < 32; ++j) sum += part[(g + 16 * j) * 16 + s];
  red[g][s] = sum;
  if (t < 8) lcnt[t] = 0;
  __syncthreads();
  if (t < 16) {
    float tot = 0.f;
    #pragma unroll
    for (int gg = 0; gg < 16; ++gg) tot += red[gg][t];
    if (blockIdx.x == 0) outIL[t] = tot;
    if (t < 8) {
      cnt_s[t] = (int)(tot + 0.5f);
      if (blockIdx.x == 0) counts[t] = (int)(tot + 0.5f);
    }
  }
  __syncthreads();
  int n = blockIdx.x * 256 + t;
  int e = eid[n];
  int rank = atomicAdd(&lcnt[e], 1);
  __syncthreads();
  if (t < 8) lbase[t] = atomicAdd(&fill[t], lcnt[t]);
  __syncthreads();
  int off = 0;
  #pragma unroll
  for (int i = 0; i < 8; ++i) if (i < e) off += cnt_s[i];
  bucket[off + lbase[e] + rank] = n;
}

// ---------------------------------------------------------------------------
// kD9: h_sorted = lora_a[e] @ x[bucket]. 519 blocks, 16 sorted tokens/tile;
// register tile 4 tok x 4 r.
// ---------------------------------------------------------------------------
__global__ __launch_bounds__(256) void kD9(const float* __restrict__ x,
    const float* __restrict__ la, const int* __restrict__ counts,
    const int* __restrict__ bucket, float* __restrict__ h) {
  __shared__ float xl[16 * 132];
  __shared__ float wl[16 * 132];
  __shared__ float accd[16 * 16 * 20];
  __shared__ float hS[16 * 20];
  __shared__ int toks[16];
  int tile = blockIdx.x;
  int e = -1, jt = 0, off = 0;
  { int tot = 0, o = 0;
    #pragma unroll
    for (int i = 0; i < 8; ++i) {
      int c = counts[i]; int nt = (c + 15) >> 4;
      if (e < 0 && tile < tot + nt) { e = i; jt = tile - tot; off = o; }
      tot += nt; o += c;
    } }
  if (e < 0) return;
  int cnt = counts[e];
  int p0 = off + (jt << 4);
  int valid = min(16, cnt - (jt << 4));
  int t = threadIdx.x;
  if (t < 16) toks[t] = bucket[p0 + min(t, valid - 1)];
  __syncthreads();
  int tokq = t & 3, rg = (t >> 2) & 3, kh = t >> 4;
  int tx = t >> 4, jx = t & 15;
  const float* xsrc = x + (size_t)toks[tx] * DIM + (jx << 3);
  const float* wsrc = la + (size_t)e * (NR * DIM) + (size_t)tx * DIM + (jx << 3);
  float4 xa0 = *(const float4*)(xsrc);
  float4 xa1 = *(const float4*)(xsrc + 4);
  float4 wa0 = *(const float4*)(wsrc);
  float4 wa1 = *(const float4*)(wsrc + 4);
  float4 acc0 = Z4, acc1 = Z4, acc2 = Z4, acc3 = Z4;
  for (int c = 0; c < 8; ++c) {
    __syncthreads();
    *(float4*)&xl[tx * 132 + (jx << 3)]     = xa0;
    *(float4*)&xl[tx * 132 + (jx << 3) + 4] = xa1;
    *(float4*)&wl[tx * 132 + (jx << 3)]     = wa0;
    *(float4*)&wl[tx * 132 + (jx << 3) + 4] = wa1;
    __syncthreads();
    if (c < 7) {
      int ko = (c + 1) << 7;
      xa0 = *(const float4*)(xsrc + ko);
      xa1 = *(const float4*)(xsrc + ko + 4);
      wa0 = *(const float4*)(wsrc + ko);
      wa1 = *(const float4*)(wsrc + ko + 4);
    }
    #pragma unroll
    for (int k4 = 0; k4 < 2; ++k4) {
      int kk = (kh << 3) + (k4 << 2);
      float4 xv0 = *(const float4*)&xl[(tokq +  0) * 132 + kk];
      float4 xv1 = *(const float4*)&xl[(tokq +  4) * 132 + kk];
      float4 xv2 = *(const float4*)&xl[(tokq +  8) * 132 + kk];
      float4 xv3 = *(const float4*)&xl[(tokq + 12) * 132 + kk];
      const float* wb = &wl[(rg << 2) * 132 + kk];
      float4 a0 = *(const float4*)(wb + 0);
      float4 a1 = *(const float4*)(wb + 132);
      float4 a2 = *(const float4*)(wb + 264);
      float4 a3 = *(const float4*)(wb + 396);
      DOT4ACC(acc0.x, xv0, a0); DOT4ACC(acc0.y, xv0, a1); DOT4ACC(acc0.z, xv0, a2); DOT4ACC(acc0.w, xv0, a3);
      DOT4ACC(acc1.x, xv1, a0); DOT4ACC(acc1.y, xv1, a1); DOT4ACC(acc1.z, xv1, a2); DOT4ACC(acc1.w, xv1, a3);
      DOT4ACC(acc2.x, xv2, a0); DOT4ACC(acc2.y, xv2, a1); DOT4ACC(acc2.z, xv2, a2); DOT4ACC(acc2.w, xv2, a3);
      DOT4ACC(acc3.x, xv3, a0); DOT4ACC(acc3.y, xv3, a1); DOT4ACC(acc3.z, xv3, a2); DOT4ACC(acc3.w, xv3, a3);
    }
  }
  { int b = kh * 320 + (rg << 2);
    *(float4*)&accd[b + (tokq +  0) * 20] = acc0;
    *(float4*)&accd[b + (tokq +  4) * 20] = acc1;
    *(float4*)&accd[b + (tokq +  8) * 20] = acc2;
    *(float4*)&accd[b + (tokq + 12) * 20] = acc3; }
  __syncthreads();
  { int ts = t >> 4, rr = t & 15;
    float s = 0.f;
    #pragma unroll
    for (int k2 = 0; k2 < 16; ++k2) s += accd[k2 * 320 + ts * 20 + rr];
    hS[ts * 20 + rr] = s; }
  __syncthreads();
  if (t < 64) {
    int tk = t >> 2, rq = (t & 3) << 2;
    if (tk < valid) {
      float4 v = make_float4(hS[tk * 20 + rq + 0], hS[tk * 20 + rq + 1],
                             hS[tk * 20 + rq + 2], hS[tk * 20 + rq + 3]);
      *(float4*)(h + (size_t)(p0 + tk) * NR + rq) = v;
    }
  }
}

// ---------------------------------------------------------------------------
// kE: out[n] = lora_b[e] @ h_sorted. Tiles: 64 tokens x 256 outs.
// ---------------------------------------------------------------------------
__global__ __launch_bounds__(256) void kE(const float* __restrict__ h,
    const float* __restrict__ lb, const int* __restrict__ counts,
    const int* __restrict__ bucket, float* __restrict__ out) {
  __shared__ float bt[16][260];
  __shared__ float ht[16][64];
  __shared__ int toks[64];
  int tile = blockIdx.y;
  int e = -1, jt = 0, off = 0;
  { int tot = 0, o = 0;
    #pragma unroll
    for (int i = 0; i < 8; ++i) {
      int c = counts[i]; int nt = (c + 63) >> 6;
      if (e < 0 && tile < tot + nt) { e = i; jt = tile - tot; off = o; }
      tot += nt; o += c;
    } }
  if (e < 0) return;
  int cnt = counts[e];
  int p0 = off + (jt << 6);
  int valid = min(64, cnt - (jt << 6));
  int o0 = blockIdx.x << 8;
  int t = threadIdx.x;
  if (t < 64) toks[t] = bucket[p0 + min(t, valid - 1)];
  const float* bbase = lb + ((size_t)e * NO + o0) * NR;
  #pragma unroll
  for (int kk = 0; kk < 4; ++kk) {
    int idx = (kk << 8) + t;
    int o = idx >> 2, rq = (idx & 3) << 2;
    float4 v = *(const float4*)(bbase + o * NR + rq);
    bt[rq + 0][o] = v.x; bt[rq + 1][o] = v.y; bt[rq + 2][o] = v.z; bt[rq + 3][o] = v.w;
  }
  { int tok = t >> 2, rq = (t & 3) << 2;
    float4 v = *(const float4*)(h + (size_t)(p0 + min(tok, valid - 1)) * NR + rq);
    ht[rq + 0][tok] = v.x; ht[rq + 1][tok] = v.y; ht[rq + 2][tok] = v.z; ht[rq + 3][tok] = v.w; }
  __syncthreads();
  int og = t & 31, tokg = t >> 5;
  int ob = og << 2, tb = tokg << 3;
  float4 z = Z4;
  float4 aL0=z,aL1=z,aL2=z,aL3=z,aL4=z,aL5=z,aL6=z,aL7=z;
  float4 aH0=z,aH1=z,aH2=z,aH3=z,aH4=z,aH5=z,aH6=z,aH7=z;
  #pragma unroll
  for (int r = 0; r < 16; ++r) {
    float4 blo = *(const float4*)&bt[r][ob];
    float4 bhi = *(const float4*)&bt[r][ob + 128];
    float4 h0  = *(const float4*)&ht[r][tb];
    float4 h1  = *(const float4*)&ht[r][tb + 4];
    FMA4(aL0, h0.x, blo); FMA4(aH0, h0.x, bhi);
    FMA4(aL1, h0.y, blo); FMA4(aH1, h0.y, bhi);
    FMA4(aL2, h0.z, blo); FMA4(aH2, h0.z, bhi);
    FMA4(aL3, h0.w, blo); FMA4(aH3, h0.w, bhi);
    FMA4(aL4, h1.x, blo); FMA4(aH4, h1.x, bhi);
    FMA4(aL5, h1.y, blo); FMA4(aH5, h1.y, bhi);
    FMA4(aL6, h1.z, blo); FMA4(aH6, h1.z, bhi);
    FMA4(aL7, h1.w, blo); FMA4(aH7, h1.w, bhi);
  }
  #define ST(J, AL, AH) { int tt = tb + (J); if (tt < valid) { \
      float* p = out + (size_t)toks[tt] * NO + o0 + ob; \
      *(float4*)p = AL; *(float4*)(p + 128) = AH; } }
  ST(0, aL0, aH0); ST(1, aL1, aH1); ST(2, aL2, aH2); ST(3, aL3, aH3);
  ST(4, aL4, aH4); ST(5, aL5, aH5); ST(6, aL6, aH6); ST(7, aL7, aH7);
  #undef ST
}

// ---------------------------------------------------------------------------
extern "C" void kernel_launch(void* const* d_in, const int* in_sizes, int n_in,
                              void* d_out, int out_size, void* d_ws, size_t ws_size,
                              hipStream_t stream) {
  const float* x  = (const float*)d_in[0];
  const float* wg = (const float*)d_in[1];
  const float* wn = (const float*)d_in[2];
  const float* la = (const float*)d_in[3];
  const float* lb = (const float*)d_in[4];
  const float* nz = (const float*)d_in[5];
  float* out = (float*)d_out;

  char* ws = (char*)d_ws;
  float* h        = (float*)(ws);                 // 524288 B
  int*   eid      = (int*)  (ws + 524288);        // 32768 B
  int*   bucket   = (int*)  (ws + 557056);        // 32768 B
  float* partials = (float*)(ws + 589824);        // 32768 B (512*16*4)
  int*   counts   = (int*)  (ws + 622592);        // 32 B
  int*   fill     = (int*)  (ws + 622624);        // 32 B

  kA9<<<512, 256, 0, stream>>>(x, wg, wn, nz, eid, partials, fill);
  kC<<<32, 256, 0, stream>>>(partials, eid, fill, bucket, out + OUT_ELEMS, counts);
  kD9<<<519, 256, 0, stream>>>(x, la, counts, bucket, h);
  kE<<<dim3(12, 135), 256, 0, stream>>>(h, lb, counts, bucket, out);
}